// Round 11
// baseline (30.895 us; speedup 1.0000x reference)
//
#include <hip/hip_runtime.h>

// LePE window attention, 32x32x16 bf16 MFMA, reg-P via v_permlane32_swap_b32.
// R11: score-tile double-pipeline — QK^T(kt+1) MFMAs issue BEFORE softmax/PV
// of kt, so MFMA latency hides under the exp2/cvtpk VALU stretch. kf double-
// buffered one tile ahead; static register naming throughout (no runtime idx).
// Structure: 256 blocks x 1024 threads (16 waves), K/V staged once per
// (window, head). LDS = K[512][40] + V^T[32][536] bf16 = 73.5 KB.

namespace {
constexpr int Bn   = 8;
constexpr int Ww   = 64;
constexpr int Cc   = 128;
constexpr int HD   = 32;
constexpr int WSP  = 8;
constexpr int NTOK = 512;
constexpr int LL   = 64 * 64;
// 32^-0.5 * log2(e): exp(s) == exp2(s') with scale folded into Q
constexpr float SCALE_L2E = 0.17677669529663687f * 1.4426950408889634f;
constexpr int KPAD = 40;   // K row stride in shorts (80B rows -> 16B-aligned frags)
constexpr int VPAD = 536;  // V^T row stride in shorts (1072B rows -> 16B-aligned)
}

typedef __bf16 bf16x8 __attribute__((ext_vector_type(8)));
typedef float  f32x16 __attribute__((ext_vector_type(16)));
typedef unsigned int uint32x4 __attribute__((ext_vector_type(4)));

// dst.lo = bf16(x), dst.hi = bf16(y) — single VALU op (RNE)
__device__ inline unsigned cvtpk(float x, float y) {
    unsigned r;
    asm("v_cvt_pk_bf16_f32 %0, %1, %2" : "=v"(r) : "v"(x), "v"(y));
    return r;
}

__global__ __launch_bounds__(1024, 4) void attn_kernel(const float* __restrict__ qkv,
                                                       const float* __restrict__ cw,
                                                       const float* __restrict__ cb,
                                                       float* __restrict__ out) {
    const int blk = blockIdx.x;          // 0..255
    const int w   = blk >> 2;            // window 0..63
    const int h   = blk & 3;             // head
    const int b   = w >> 3;
    const int wb  = w & 7;
    const int tid = threadIdx.x;         // 0..1023
    const int wv  = tid >> 6;            // wave 0..15 -> 32 q rows each
    const int lane = tid & 63;
    const int l31 = lane & 31;
    const int h5  = lane >> 5;

    const float* qp = qkv;
    const float* kp = qkv + (size_t)Bn * LL * Cc;
    const float* vp = qkv + (size_t)2 * Bn * LL * Cc;

    __shared__ short K_lds[NTOK][KPAD];
    __shared__ short VT_lds[HD][VPAD];

    // ---- Q fragments: q tok = wv*32 + l31, d = dc*16 + h5*8 + e ----
    const int qtok = wv * 32 + l31;
    const int qlqi = (qtok >> 3) * Ww + wb * WSP + (qtok & 7);
    bf16x8 qf[2];
    {
        const float* p = qp + ((size_t)b * LL + qlqi) * Cc + h * HD + h5 * 8;
#pragma unroll
        for (int dc = 0; dc < 2; ++dc) {
            float4 a = *reinterpret_cast<const float4*>(p + dc * 16);
            float4 c = *reinterpret_cast<const float4*>(p + dc * 16 + 4);
            uint32x4 u;
            u.x = cvtpk(a.x * SCALE_L2E, a.y * SCALE_L2E);
            u.y = cvtpk(a.z * SCALE_L2E, a.w * SCALE_L2E);
            u.z = cvtpk(c.x * SCALE_L2E, c.y * SCALE_L2E);
            u.w = cvtpk(c.z * SCALE_L2E, c.w * SCALE_L2E);
            qf[dc] = __builtin_bit_cast(bf16x8, u);
        }
    }

    // ---- stage K and V^T (bf16), token-pair scheme: 2048 items / 1024 thr ----
    for (int i = tid; i < (NTOK / 2) * 8; i += 1024) {
        const int tp = i >> 3, j = i & 7;      // token pair, d-group
        const int t0 = tp * 2, t1 = t0 + 1;
        const int lqi0 = (t0 >> 3) * Ww + wb * WSP + (t0 & 7);  // lqi1 = lqi0+1
        const size_t b0 = ((size_t)b * LL + lqi0) * Cc + h * HD + j * 4;
        const float4 k0 = *reinterpret_cast<const float4*>(kp + b0);
        const float4 k1 = *reinterpret_cast<const float4*>(kp + b0 + Cc);
        uint2 pk0, pk1;
        pk0.x = cvtpk(k0.x, k0.y);  pk0.y = cvtpk(k0.z, k0.w);
        pk1.x = cvtpk(k1.x, k1.y);  pk1.y = cvtpk(k1.z, k1.w);
        *reinterpret_cast<uint2*>(&K_lds[t0][j * 4]) = pk0;
        *reinterpret_cast<uint2*>(&K_lds[t1][j * 4]) = pk1;
        const float4 v0 = *reinterpret_cast<const float4*>(vp + b0);
        const float4 v1 = *reinterpret_cast<const float4*>(vp + b0 + Cc);
        *reinterpret_cast<unsigned*>(&VT_lds[j * 4 + 0][t0]) = cvtpk(v0.x, v1.x);
        *reinterpret_cast<unsigned*>(&VT_lds[j * 4 + 1][t0]) = cvtpk(v0.y, v1.y);
        *reinterpret_cast<unsigned*>(&VT_lds[j * 4 + 2][t0]) = cvtpk(v0.z, v1.z);
        *reinterpret_cast<unsigned*>(&VT_lds[j * 4 + 3][t0]) = cvtpk(v0.w, v1.w);
    }
    __syncthreads();   // the only barrier

    f32x16 acc = (f32x16)(0.f);
    float lsum = 0.f;
    const f32x16 z16 = (f32x16)(0.f);

    auto load_kf = [&](int kt, bf16x8* kf) {
        const int krow = kt * 32 + l31;
#pragma unroll
        for (int dc = 0; dc < 2; ++dc)
            kf[dc] = __builtin_bit_cast(bf16x8,
                *reinterpret_cast<const uint32x4*>(&K_lds[krow][dc * 16 + h5 * 8]));
    };

    // ---- prologue: s_cur for kt=0, kfB holds kt=1 ----
    bf16x8 kfA[2], kfB[2];
    load_kf(0, kfA);
    f32x16 s_cur = z16;
    s_cur = __builtin_amdgcn_mfma_f32_32x32x16_bf16(kfA[0], qf[0], s_cur, 0, 0, 0);
    s_cur = __builtin_amdgcn_mfma_f32_32x32x16_bf16(kfA[1], qf[1], s_cur, 0, 0, 0);
    load_kf(1, kfB);

    // ---- main loop: 16 tiles of 32 keys, barrier-free, s double-pipelined ----
    for (int kt = 0; kt < 16; ++kt) {
        // issue next tile's QK^T first — retires under the softmax VALU below
        __builtin_amdgcn_s_setprio(1);
        f32x16 s_next = z16;
        s_next = __builtin_amdgcn_mfma_f32_32x32x16_bf16(kfB[0], qf[0], s_next, 0, 0, 0);
        s_next = __builtin_amdgcn_mfma_f32_32x32x16_bf16(kfB[1], qf[1], s_next, 0, 0, 0);
        __builtin_amdgcn_s_setprio(0);
        load_kf((kt + 2) & 15, kfB);
        uint32x4 vu0, vu1;
        {
            const int kcol = kt * 32 + h5 * 8;
            vu0 = *reinterpret_cast<const uint32x4*>(&VT_lds[l31][kcol]);
            vu1 = *reinterpret_cast<const uint32x4*>(&VT_lds[l31][kcol + 16]);
        }
        __builtin_amdgcn_sched_barrier(0);   // keep exp chain below the MFMAs

        // softmax of s_cur; lane holds S^T[k][q=l31],
        // k = (reg&3) + 8*(reg>>2) + 4*h5 + kt*32
        float pe[16];
#pragma unroll
        for (int i = 0; i < 16; ++i) pe[i] = __builtin_amdgcn_exp2f(s_cur[i]);
        {
            float t0 = 0.f, t1 = 0.f;
#pragma unroll
            for (int i = 0; i < 8; ++i) { t0 += pe[2 * i]; t1 += pe[2 * i + 1]; }
            lsum += t0 + t1;
        }
        unsigned dw[8];
#pragma unroll
        for (int i = 0; i < 8; ++i) dw[i] = cvtpk(pe[2 * i], pe[2 * i + 1]);

        // PV: per 16-key window kw, redistribute P across the h5 halves with
        // 2x v_permlane32_swap_b32 (vdst_hi <-> vsrc_lo), then one MFMA.
        {
            unsigned a0 = dw[0], b0 = dw[2], a1 = dw[1], b1 = dw[3];
            asm("v_permlane32_swap_b32 %0, %1" : "+v"(a0), "+v"(b0));
            asm("v_permlane32_swap_b32 %0, %1" : "+v"(a1), "+v"(b1));
            uint32x4 pu; pu.x = a0; pu.y = a1; pu.z = b0; pu.w = b1;
            acc = __builtin_amdgcn_mfma_f32_32x32x16_bf16(
                __builtin_bit_cast(bf16x8, pu), __builtin_bit_cast(bf16x8, vu0),
                acc, 0, 0, 0);
        }
        {
            unsigned a0 = dw[4], b0 = dw[6], a1 = dw[5], b1 = dw[7];
            asm("v_permlane32_swap_b32 %0, %1" : "+v"(a0), "+v"(b0));
            asm("v_permlane32_swap_b32 %0, %1" : "+v"(a1), "+v"(b1));
            uint32x4 pu; pu.x = a0; pu.y = a1; pu.z = b0; pu.w = b1;
            acc = __builtin_amdgcn_mfma_f32_32x32x16_bf16(
                __builtin_bit_cast(bf16x8, pu), __builtin_bit_cast(bf16x8, vu1),
                acc, 0, 0, 0);
        }
        s_cur = s_next;
    }

    // ---- softmax denominator: other k-half lives in the partner lane ----
    lsum += __shfl_xor(lsum, 32);
    const float inv = 1.f / lsum;

    // ---- LePE conv: lane owns channel d = l31 of head h ----
    const int ch = h * HD + l31;
    float wreg[9];
#pragma unroll
    for (int wi = 0; wi < 9; ++wi) wreg[wi] = cw[ch * 9 + wi];
    const float bias = cb[ch];

    const int tok0 = wv * 32;
    // Packed V halo: 52 bf16 toks [tok0 + 4*h5 - 12, +40) as 26 uints.
    // Needed tap range rel. tok0+4h5 is [-9,+36]; clamped chunk slots are only
    // tokens <0 / >=512, all rowok-guarded below.
    unsigned hw[26];
    {
        const int segbase = tok0 + 4 * h5 - 12;
#pragma unroll
        for (int c2 = 0; c2 < 13; ++c2) {
            int t = segbase + 4 * c2;
            t = t < 0 ? 0 : (t > NTOK - 4 ? NTOK - 4 : t);
            const uint2 u = *reinterpret_cast<const uint2*>(&VT_lds[l31][t]);
            hw[c2 * 2 + 0] = u.x;
            hw[c2 * 2 + 1] = u.y;
        }
    }

    // ---- epilogue: normalize + conv + store, per accumulator element ----
#pragma unroll
    for (int r = 0; r < 16; ++r) {
        const int c_r = (r & 3) + 8 * (r >> 2);           // q row offset (compile-time)
        const float iv = __shfl(inv, c_r + 4 * h5);       // q_r's denominator
        const int tok = tok0 + c_r + 4 * h5;
        float cv = bias;
#pragma unroll
        for (int dy = -1; dy <= 1; ++dy) {
            const bool rowok = (unsigned)(tok + dy * 8) < (unsigned)NTOK;
#pragma unroll
            for (int dx = -1; dx <= 1; ++dx) {
                const int idx = c_r + 12 + dy * 8 + dx;   // compile-time, in [3,48]
                const unsigned word = hw[idx >> 1];
                const float tap = __builtin_bit_cast(float,
                    (idx & 1) ? (word & 0xFFFF0000u) : (word << 16));
                bool ok = rowok;
                if (dx == -1) ok = ok && (((r & 3) != 0) || (h5 != 0));  // wc > 0
                if (dx == +1) ok = ok && (((r & 3) != 3) || (h5 == 0));  // wc < 7
                cv += ok ? wreg[(dy + 1) * 3 + (dx + 1)] * tap : 0.f;
            }
        }
        const int lqi = (tok >> 3) * Ww + wb * WSP + (tok & 7);
        out[((size_t)b * LL + lqi) * Cc + ch] = acc[r] * iv + cv;
    }
}

extern "C" void kernel_launch(void* const* d_in, const int* in_sizes, int n_in,
                              void* d_out, int out_size, void* d_ws, size_t ws_size,
                              hipStream_t stream) {
    const float* qkv = (const float*)d_in[0];
    const float* cw  = (const float*)d_in[1];
    const float* cb  = (const float*)d_in[2];
    float* out = (float*)d_out;

    attn_kernel<<<256, 1024, 0, stream>>>(qkv, cw, cb, out);
}